// Round 2
// baseline (805.909 us; speedup 1.0000x reference)
//
#include <hip/hip_runtime.h>
#include <stdint.h>
#include <math.h>

// Problem dims
#define BDIM 8192
#define TDIM 8192
#define FDIM 768
#define PDIM 512
#define HDIM 1024
#define NEXP 4
#define NCAT 5376  // 4*1024 (experts) + 1024 (ds) + 256 (router)

using short4v = __attribute__((ext_vector_type(4))) short;
using short8 = __attribute__((ext_vector_type(8))) short;
using f32x4  = __attribute__((ext_vector_type(4))) float;

__device__ __forceinline__ short f2bf(float f) {
  uint32_t u = __builtin_bit_cast(uint32_t, f);
  u += 0x7fffu + ((u >> 16) & 1u);   // RNE
  return (short)(u >> 16);
}
__device__ __forceinline__ float bf2f(short s) {
  uint32_t u = ((uint32_t)(uint16_t)s) << 16;
  return __builtin_bit_cast(float, u);
}
__device__ __forceinline__ float gelu_exact(float x) {
  return 0.5f * x * (1.0f + erff(x * 0.70710678118654752f));
}

#define GLDS(gp, lp) __builtin_amdgcn_global_load_lds( \
    (const __attribute__((address_space(1))) void*)(gp), \
    (__attribute__((address_space(3))) void*)(lp), 16, 0, 0)

// ---------------------------------------------------------------------------
// 256x256-tile 8-phase GEMM (m201 template, BK=32 variant):
// C[M,N] = A[M,K] @ B[N,K]^T, bf16 inputs.
// 512 threads = 8 waves (2M x 4N); wave tile 128x64; phase = one 64-row half
// of the wave tile x full BK -> 16 MFMA/phase, 2 phases per K-tile of 32.
// LDS: 16 half-tile slots x 8 KiB = 128 KiB (4 K-tile buffers).  Stream of
// half-tiles per K-tile: A0 (block rows 0-127), A1, B0, B1.  Each phase
// stages 2 half-tiles at lead 9 (1 GLDS dwordx4/thread each); slot reuse
// distance 16 guarantees every overwrite targets a half-tile whose last
// ds_read was pinned (lgkmcnt(0)+barrier) at least one phase earlier.
// Counted s_waitcnt vmcnt(5) once per K-tile (tail: 4/0) placed BEFORE the
// tile's closing barrier -> block-wide landing guarantee, loads stay in
// flight across barriers.  XOR swizzle (S ^= ((S>>7)&7)<<4) applied to the
// global SOURCE of global_load_lds (dest linear) and to ds_read offsets.
// MODE 0: +bias[col], gelu, store bf16.  MODE 2: *scale, store f32.
// Requires K >= 128 (NT >= 4), K % 32 == 0, M,N % 256 == 0.
// ---------------------------------------------------------------------------
template <int MODE>
__global__ __launch_bounds__(512, 2)
void gemm256(const short* __restrict__ A, int lda,
             const short* __restrict__ B, int ldb,
             void* __restrict__ C, int ldc, int K,
             const float* __restrict__ bias,
             const float* __restrict__ scale_ptr)
{
  __shared__ short lds_s[65536];  // 16 slots x 4096 shorts = 128 KiB
  const int t    = threadIdx.x;
  const int lane = t & 63;
  const int wave = t >> 6;
  const int wr   = wave >> 2;   // 0..1  (M)
  const int wc   = wave & 3;    // 0..3  (N)
  const int l15  = lane & 15;
  const int quad = lane >> 4;
  const int m0 = blockIdx.y * 256;
  const int n0 = blockIdx.x * 256;
  const int NT = K >> 5;        // K-tiles of 32

  // ---- staging: pre-swizzled per-lane global source, linear LDS dest ----
  const uint32_t Sl   = (uint32_t)t * 16u;                    // byte slot in 8 KiB half-tile
  const uint32_t Ssw  = Sl ^ (((Sl >> 7) & 7u) << 4);         // involution (bits 7-9 -> 4-6)
  const uint32_t srow = Ssw >> 6;                             // 0..127 within half-tile
  const uint32_t sk   = ((Ssw >> 4) & 3u) * 8u;               // k offset in shorts
  const short* gA    = A + (size_t)(m0 + srow) * lda + sk;
  const short* gA128 = A + (size_t)(m0 + 128 + srow) * lda + sk;
  const short* gB    = B + (size_t)(n0 + srow) * ldb + sk;
  const short* gB128 = B + (size_t)(n0 + 128 + srow) * ldb + sk;
  short* lp = lds_s + t * 8;   // within-slot dest (shorts)

  // ---- ds_read offsets (shorts within a 16K-short tile buffer), swizzled ----
  int offA0[4], offB[4];
#pragma unroll
  for (int i = 0; i < 4; ++i) {
    uint32_t S = (uint32_t)((wr * 64 + i * 16 + l15) * 64 + quad * 16);
    offA0[i] = (int)((S ^ (((S >> 7) & 7u) << 4)) >> 1);      // A-half0; A-half1 = +4096
  }
#pragma unroll
  for (int j = 0; j < 4; ++j) {
    const int c = wc * 64 + j * 16 + l15;                     // 0..255
    uint32_t S = (uint32_t)((c & 127) * 64 + quad * 16);
    offB[j] = (int)(((S ^ (((S >> 7) & 7u) << 4)) >> 1) + 8192u + (uint32_t)(c >> 7) * 4096u);
  }

  f32x4 acc[2][4][4];
#pragma unroll
  for (int h = 0; h < 2; ++h)
#pragma unroll
    for (int i = 0; i < 4; ++i)
#pragma unroll
      for (int j = 0; j < 4; ++j)
        acc[h][i][j] = (f32x4){0.f, 0.f, 0.f, 0.f};

  // ---- prologue: stage half-tiles hs=0..8 (tiles 0,1 full + A0 of tile 2) ----
  GLDS(gA,        lp +  0 * 4096);  // hs0  t0.A0
  GLDS(gA128,     lp +  1 * 4096);  // hs1  t0.A1
  GLDS(gB,        lp +  2 * 4096);  // hs2  t0.B0
  GLDS(gB128,     lp +  3 * 4096);  // hs3  t0.B1
  GLDS(gA + 32,   lp +  4 * 4096);  // hs4  t1.A0
  GLDS(gA128 + 32, lp + 5 * 4096);  // hs5  t1.A1
  GLDS(gB + 32,   lp +  6 * 4096);  // hs6  t1.B0
  GLDS(gB128 + 32, lp + 7 * 4096);  // hs7  t1.B1
  GLDS(gA + 64,   lp +  8 * 4096);  // hs8  t2.A0
  asm volatile("s_waitcnt vmcnt(5)" ::: "memory");   // tile 0 landed
  __builtin_amdgcn_s_barrier();

  for (int T = 0; T < NT; ++T) {
    const short* tile = lds_s + ((T & 3) << 14);     // 16384 shorts per buffer
    const int k2 = (T + 2) << 5;
    const int k3 = (T + 3) << 5;
    short8 a[4], b[4];

    // ============ phase 0: A-half0 x all B ============
    if (T + 2 < NT) {
      const int s2 = ((T + 2) & 3) << 14;
      GLDS(gA128 + k2, lp + s2 + 4096);   // hs=4T+9  A1(T+2)
      GLDS(gB    + k2, lp + s2 + 8192);   // hs=4T+10 B0(T+2)
    }
#pragma unroll
    for (int j = 0; j < 4; ++j) b[j] = *(const short8*)(tile + offB[j]);
#pragma unroll
    for (int i = 0; i < 4; ++i) a[i] = *(const short8*)(tile + offA0[i]);
    __builtin_amdgcn_s_barrier();
    asm volatile("s_waitcnt lgkmcnt(0)" ::: "memory");
    __builtin_amdgcn_sched_barrier(0);
    __builtin_amdgcn_s_setprio(1);
#pragma unroll
    for (int i = 0; i < 4; ++i)
#pragma unroll
      for (int j = 0; j < 4; ++j)
        acc[0][i][j] = __builtin_amdgcn_mfma_f32_16x16x32_bf16(a[i], b[j], acc[0][i][j], 0, 0, 0);
    __builtin_amdgcn_s_setprio(0);
    __builtin_amdgcn_s_barrier();

    // ============ phase 1: A-half1 x all B (b[] reused in regs) ============
    if (T + 2 < NT) {
      const int s2 = ((T + 2) & 3) << 14;
      GLDS(gB128 + k2, lp + s2 + 12288);  // hs=4T+11 B1(T+2)
    }
    if (T + 3 < NT) {
      const int s3 = ((T + 3) & 3) << 14;
      GLDS(gA + k3, lp + s3);             // hs=4T+12 A0(T+3)
    }
#pragma unroll
    for (int i = 0; i < 4; ++i) a[i] = *(const short8*)(tile + offA0[i] + 4096);
    __builtin_amdgcn_s_barrier();
    asm volatile("s_waitcnt lgkmcnt(0)" ::: "memory");
    __builtin_amdgcn_sched_barrier(0);
    __builtin_amdgcn_s_setprio(1);
#pragma unroll
    for (int i = 0; i < 4; ++i)
#pragma unroll
      for (int j = 0; j < 4; ++j)
        acc[1][i][j] = __builtin_amdgcn_mfma_f32_16x16x32_bf16(a[i], b[j], acc[1][i][j], 0, 0, 0);
    __builtin_amdgcn_s_setprio(0);
    // ---- K-tile boundary: counted vmcnt BEFORE the closing barrier so the
    // barrier gives a block-wide landing guarantee for tile T+1; loads for
    // tiles T+2/T+3 stay in flight.
    if (T < NT - 1) {
      if      (T < NT - 3)  asm volatile("s_waitcnt vmcnt(5)" ::: "memory");
      else if (T == NT - 3) asm volatile("s_waitcnt vmcnt(4)" ::: "memory");
      else                  asm volatile("s_waitcnt vmcnt(0)" ::: "memory");
      __builtin_amdgcn_s_barrier();
    }
  }

  // ---- epilogue (scale load kept here so no vector load perturbs vmcnt) ----
  float scale = 1.f;
  if (MODE == 2) scale = expf(scale_ptr[0]);
#pragma unroll
  for (int mh = 0; mh < 2; ++mh) {
#pragma unroll
    for (int i = 0; i < 4; ++i) {
      const int rowb = m0 + mh * 128 + wr * 64 + i * 16 + quad * 4;
#pragma unroll
      for (int j = 0; j < 4; ++j) {
        const int col = n0 + wc * 64 + j * 16 + l15;
        const float bv = (MODE == 2) ? 0.f : bias[col];
        f32x4 v = acc[mh][i][j];
#pragma unroll
        for (int r = 0; r < 4; ++r) {
          float x = v[r];
          if (MODE == 0) {
            ((short*)C)[(size_t)(rowb + r) * ldc + col] = f2bf(gelu_exact(x + bv));
          } else if (MODE == 1) {
            ((float*)C)[(size_t)(rowb + r) * ldc + col] = x + bv;
          } else {
            ((float*)C)[(size_t)(rowb + r) * ldc + col] = x * scale;
          }
        }
      }
    }
  }
}

// ---------------------------------------------------------------------------
// Shared GEMM body (128x128, m97-style) — kept for the small GEMMs
// (proj N=512, resid N=768: too few 256^2 blocks to fill the chip).
// ---------------------------------------------------------------------------
template <int MODE>
__device__ __forceinline__ void gemm_body(
    const short* __restrict__ A, int lda,
    const short* __restrict__ B, int ldb,
    void* __restrict__ C, int ldc, int K,
    const float* __restrict__ bias, float scale,
    int m0, int n0)
{
  __shared__ short sA[4096];  // 128 x 32
  __shared__ short sB[4096];
  const int t    = threadIdx.x;
  const int lane = t & 63;
  const int wave = t >> 6;
  const int wm = (wave >> 1) * 64;
  const int wn = (wave & 1) * 64;
  const int l15  = lane & 15;
  const int quad = lane >> 4;

  f32x4 acc[4][4];
#pragma unroll
  for (int i = 0; i < 4; ++i)
#pragma unroll
    for (int j = 0; j < 4; ++j)
      acc[i][j] = (f32x4){0.f, 0.f, 0.f, 0.f};

  const int rr = t >> 2;
  const int cc = (t & 3) * 8;
  const short* gA0 = A + (size_t)(m0 + rr) * lda + cc;
  const short* gA1 = A + (size_t)(m0 + 64 + rr) * lda + cc;
  const short* gB0 = B + (size_t)(n0 + rr) * ldb + cc;
  const short* gB1 = B + (size_t)(n0 + 64 + rr) * ldb + cc;
  short* lA0 = sA + t * 8;
  short* lA1 = sA + 2048 + t * 8;
  short* lB0 = sB + t * 8;
  short* lB1 = sB + 2048 + t * 8;

  for (int k0 = 0; k0 < K; k0 += 32) {
    GLDS(gA0 + k0, lA0);
    GLDS(gA1 + k0, lA1);
    GLDS(gB0 + k0, lB0);
    GLDS(gB1 + k0, lB1);
    __syncthreads();
    short8 af[4], bfr[4];
#pragma unroll
    for (int i = 0; i < 4; ++i)
      af[i] = *(const short8*)(sA + (wm + i * 16 + l15) * 32 + quad * 8);
#pragma unroll
    for (int j = 0; j < 4; ++j)
      bfr[j] = *(const short8*)(sB + (wn + j * 16 + l15) * 32 + quad * 8);
#pragma unroll
    for (int i = 0; i < 4; ++i)
#pragma unroll
      for (int j = 0; j < 4; ++j)
        acc[i][j] = __builtin_amdgcn_mfma_f32_16x16x32_bf16(af[i], bfr[j], acc[i][j], 0, 0, 0);
    __syncthreads();
  }

#pragma unroll
  for (int i = 0; i < 4; ++i) {
#pragma unroll
    for (int j = 0; j < 4; ++j) {
      const int col = n0 + wn + j * 16 + l15;
      float bv = (MODE == 2) ? 0.f : bias[col];
#pragma unroll
      for (int r = 0; r < 4; ++r) {
        const int row = m0 + wm + i * 16 + quad * 4 + r;  // C/D: col=lane&15, row=quad*4+reg
        float v = acc[i][j][r];
        if (MODE == 0) {
          v = gelu_exact(v + bv);
          ((short*)C)[(size_t)row * ldc + col] = f2bf(v);
        } else if (MODE == 1) {
          ((float*)C)[(size_t)row * ldc + col] = v + bv;
        } else {
          ((float*)C)[(size_t)row * ldc + col] = v * scale;
        }
      }
    }
  }
}

template <int MODE>
__global__ __launch_bounds__(256, 2)
void gemm_bt(const short* __restrict__ A, int lda,
             const short* __restrict__ B, int ldb,
             void* __restrict__ C, int ldc, int K,
             const float* __restrict__ bias,
             const float* __restrict__ scale_ptr)
{
  float scale = 1.f;
  if (MODE == 2) scale = expf(scale_ptr[0]);
  gemm_body<MODE>(A, lda, B, ldb, C, ldc, K, bias, scale,
                  blockIdx.y * 128, blockIdx.x * 128);
}

// both projections in one launch: z=0 -> text@Wt.T (cols 0..511),
// z=1 -> image@Wi.T (cols 512..1023); C is comb [B,1024] bf16
__global__ __launch_bounds__(256, 2)
void gemm_proj(const short* __restrict__ textb, const short* __restrict__ imgb,
               const short* __restrict__ Wtb, const short* __restrict__ Wib,
               const float* __restrict__ bt, const float* __restrict__ bi,
               short* __restrict__ comb)
{
  const int z = blockIdx.z;
  const short* A = z ? imgb : textb;
  const short* B = z ? Wib : Wtb;
  const float* bias = z ? bi : bt;
  short* C = comb + (z ? 512 : 0);
  gemm_body<0>(A, FDIM, B, FDIM, C, 1024, FDIM, bias, 1.f,
               blockIdx.y * 128, blockIdx.x * 128);
}

// ---------------------------------------------------------------------------
// One kernel for ALL f32->bf16 conversions + bias concat.
// ---------------------------------------------------------------------------
#define SEG0 1572864u   // text   (8192*768/4)
#define SEG1 3145728u   // image
#define SEG2 3244032u   // Wt     (512*768/4)
#define SEG3 3342336u   // Wi
#define SEG4 4390912u   // exp_W  (4*1024*1024/4)
#define SEG5 4653056u   // ds_W1  (1024*1024/4)
#define SEG6 4718592u   // rt_W1  (256*1024/4)
#define SEG7 4915200u   // out_W  (768*1024/4)
#define SEG8 4916544u   // bias concat (5376/4)

__global__ __launch_bounds__(256)
void prep_all(const float* __restrict__ text, const float* __restrict__ image,
              const float* __restrict__ Wt, const float* __restrict__ Wi,
              const float* __restrict__ exp_W, const float* __restrict__ ds_W1,
              const float* __restrict__ rt_W1, const float* __restrict__ out_W,
              const float* __restrict__ exp_b, const float* __restrict__ ds_b1,
              const float* __restrict__ rt_b1,
              short* __restrict__ textb, short* __restrict__ imgb,
              short* __restrict__ Wtb, short* __restrict__ Wib,
              short* __restrict__ Bcat, short* __restrict__ outWb,
              float* __restrict__ biascat)
{
  const uint32_t i = blockIdx.x * 256 + threadIdx.x;
  if (i >= SEG8) return;
  if (i >= SEG7) {  // bias concat (f32 -> f32)
    const uint32_t j = (i - SEG7) * 4;
#pragma unroll
    for (int k = 0; k < 4; ++k) {
      uint32_t idx = j + k;
      float v;
      if (idx < 4096)      v = exp_b[idx];
      else if (idx < 5120) v = ds_b1[idx - 4096];
      else                 v = rt_b1[idx - 5120];
      biascat[idx] = v;
    }
    return;
  }
  const float* s;
  short* d;
  uint32_t j;
  if (i < SEG1) {
    if (i < SEG0) { j = i;        s = text;  d = textb; }
    else          { j = i - SEG0; s = image; d = imgb;  }
  } else if (i < SEG3) {
    if (i < SEG2) { j = i - SEG1; s = Wt; d = Wtb; }
    else          { j = i - SEG2; s = Wi; d = Wib; }
  } else if (i < SEG5) {
    if (i < SEG4) { j = i - SEG3; s = exp_W; d = Bcat; }
    else          { j = i - SEG4; s = ds_W1; d = Bcat + (size_t)4096 * 1024; }
  } else {
    if (i < SEG6) { j = i - SEG5; s = rt_W1; d = Bcat + (size_t)5120 * 1024; }
    else          { j = i - SEG6; s = out_W; d = outWb; }
  }
  float4 v = ((const float4*)s)[j];
  short4v o = { f2bf(v.x), f2bf(v.y), f2bf(v.z), f2bf(v.w) };
  ((short4v*)d)[j] = o;
}

// ---------------------------------------------------------------------------
// Fused router + ds scalar + expert mixing. One block (256 thr) per row.
// ---------------------------------------------------------------------------
__global__ __launch_bounds__(256)
void moe_mix(const short* __restrict__ Hall,
             const float* __restrict__ rt_W2, const float* __restrict__ rt_b2,
             const float* __restrict__ ds_W2, const float* __restrict__ ds_b2,
             float* __restrict__ out_probs, float* __restrict__ out_ds,
             short* __restrict__ fused)
{
  const int b = blockIdx.x;
  const int t = threadIdx.x;
  const int lane = t & 63;
  const int wave = t >> 6;
  const short* h = Hall + (size_t)b * NCAT;

  float rv = bf2f(h[5120 + t]);
  float p0 = rv * rt_W2[t];
  float p1 = rv * rt_W2[256 + t];
  float p2 = rv * rt_W2[512 + t];
  float p3 = rv * rt_W2[768 + t];
  float dd = 0.f;
#pragma unroll
  for (int k = 0; k < 4; ++k)
    dd += bf2f(h[4096 + k * 256 + t]) * ds_W2[k * 256 + t];

#pragma unroll
  for (int off = 32; off; off >>= 1) {
    p0 += __shfl_xor(p0, off);
    p1 += __shfl_xor(p1, off);
    p2 += __shfl_xor(p2, off);
    p3 += __shfl_xor(p3, off);
    dd += __shfl_xor(dd, off);
  }
  __shared__ float red[5][4];
  __shared__ float bc[5];
  if (lane == 0) {
    red[0][wave] = p0; red[1][wave] = p1; red[2][wave] = p2;
    red[3][wave] = p3; red[4][wave] = dd;
  }
  __syncthreads();
  if (t == 0) {
    float l0 = red[0][0] + red[0][1] + red[0][2] + red[0][3] + rt_b2[0];
    float l1 = red[1][0] + red[1][1] + red[1][2] + red[1][3] + rt_b2[1];
    float l2 = red[2][0] + red[2][1] + red[2][2] + red[2][3] + rt_b2[2];
    float l3 = red[3][0] + red[3][1] + red[3][2] + red[3][3] + rt_b2[3];
    float d  = red[4][0] + red[4][1] + red[4][2] + red[4][3] + ds_b2[0];
    float mx = fmaxf(fmaxf(l0, l1), fmaxf(l2, l3));
    float e0 = expf(l0 - mx), e1 = expf(l1 - mx);
    float e2 = expf(l2 - mx), e3 = expf(l3 - mx);
    float inv = 1.f / (e0 + e1 + e2 + e3);
    bc[0] = e0 * inv; bc[1] = e1 * inv; bc[2] = e2 * inv; bc[3] = e3 * inv;
    bc[4] = 1.f / (1.f + expf(-d));
    out_probs[b * 4 + 0] = bc[0];
    out_probs[b * 4 + 1] = bc[1];
    out_probs[b * 4 + 2] = bc[2];
    out_probs[b * 4 + 3] = bc[3];
    out_ds[b] = bc[4];
  }
  __syncthreads();
  const float q0 = bc[0], q1 = bc[1], q2 = bc[2], q3 = bc[3];
  short* fr = fused + (size_t)b * 1024;
#pragma unroll
  for (int c = t; c < 1024; c += 256) {
    float v = q0 * bf2f(h[c])        + q1 * bf2f(h[1024 + c])
            + q2 * bf2f(h[2048 + c]) + q3 * bf2f(h[3072 + c]);
    fr[c] = f2bf(v);
  }
}

// ---------------------------------------------------------------------------
// Both normalizes in one launch.
// ---------------------------------------------------------------------------
__global__ __launch_bounds__(256)
void normalize_both(const float* __restrict__ text, const float* __restrict__ image,
                    const float* __restrict__ ds, const float* __restrict__ resid,
                    const float* __restrict__ target,
                    short* __restrict__ pred, short* __restrict__ tgtb)
{
  const int bb = blockIdx.x;
  const int t = threadIdx.x;
  float o0, o1, o2;
  short* d;
  if (bb < BDIM) {
    const float dv = ds[bb];
    const float* tx = text + (size_t)bb * FDIM;
    const float* im = image + (size_t)bb * FDIM;
    const float* s  = resid + (size_t)bb * FDIM;
    o0 = dv * tx[t]       + (1.f - dv) * im[t]       + s[t];
    o1 = dv * tx[t + 256] + (1.f - dv) * im[t + 256] + s[t + 256];
    o2 = dv * tx[t + 512] + (1.f - dv) * im[t + 512] + s[t + 512];
    d = pred + (size_t)bb * FDIM;
  } else {
    const int b = bb - BDIM;
    const float* s = target + (size_t)b * FDIM;
    o0 = s[t]; o1 = s[t + 256]; o2 = s[t + 512];
    d = tgtb + (size_t)b * FDIM;
  }
  float ss = o0 * o0 + o1 * o1 + o2 * o2;
  __shared__ float red[4];
#pragma unroll
  for (int off = 32; off; off >>= 1) ss += __shfl_xor(ss, off);
  if ((t & 63) == 0) red[t >> 6] = ss;
  __syncthreads();
  const float tot = red[0] + red[1] + red[2] + red[3];
  const float rn = 1.f / fmaxf(sqrtf(tot), 1e-12f);
  d[t]       = f2bf(o0 * rn);
  d[t + 256] = f2bf(o1 * rn);
  d[t + 512] = f2bf(o2 * rn);
}

// ---------------------------------------------------------------------------
extern "C" void kernel_launch(void* const* d_in, const int* in_sizes, int n_in,
                              void* d_out, int out_size, void* d_ws, size_t ws_size,
                              hipStream_t stream) {
  const float* image  = (const float*)d_in[0];
  const float* text   = (const float*)d_in[1];
  const float* target = (const float*)d_in[2];
  const float* Wt     = (const float*)d_in[3];
  const float* bt     = (const float*)d_in[4];
  const float* Wi     = (const float*)d_in[5];
  const float* bi     = (const float*)d_in[6];
  const float* ds_W1  = (const float*)d_in[7];
  const float* ds_b1  = (const float*)d_in[8];
  const float* ds_W2  = (const float*)d_in[9];
  const float* ds_b2  = (const float*)d_in[10];
  const float* exp_W  = (const float*)d_in[11];
  const float* exp_b  = (const float*)d_in[12];
  const float* rt_W1  = (const float*)d_in[13];
  const float* rt_b1  = (const float*)d_in[14];
  const float* rt_W2  = (const float*)d_in[15];
  const float* rt_b2  = (const float*)d_in[16];
  const float* out_W  = (const float*)d_in[17];
  const float* out_b  = (const float*)d_in[18];
  const float* logit_scale = (const float*)d_in[19];

  char* ws = (char*)d_ws;
  short* comb  = (short*)ws;  ws += (size_t)BDIM * 1024 * 2;
  short* Hall  = (short*)ws;  ws += (size_t)BDIM * NCAT * 2;
  short* fused = (short*)ws;  ws += (size_t)BDIM * 1024 * 2;
  float* resid = (float*)ws;  ws += (size_t)BDIM * FDIM * 4;
  short* pred  = (short*)ws;  ws += (size_t)BDIM * FDIM * 2;
  short* tgtb  = (short*)ws;  ws += (size_t)TDIM * FDIM * 2;
  short* textb = (short*)ws;  ws += (size_t)BDIM * FDIM * 2;
  short* imgb  = (short*)ws;  ws += (size_t)BDIM * FDIM * 2;
  short* Wtb   = (short*)ws;  ws += (size_t)PDIM * FDIM * 2;
  short* Wib   = (short*)ws;  ws += (size_t)PDIM * FDIM * 2;
  short* outWb = (short*)ws;  ws += (size_t)FDIM * HDIM * 2;
  short* Bcat  = (short*)ws;  ws += (size_t)NCAT * HDIM * 2;
  float* biascat = (float*)ws; ws += (size_t)NCAT * 4;

  float* out_logits = (float*)d_out;
  float* out_ds     = out_logits + (size_t)BDIM * TDIM;
  float* out_probs  = out_ds + BDIM;

  // 1. all conversions + bias concat in one launch
  prep_all<<<(SEG8 + 255) / 256, 256, 0, stream>>>(
      text, image, Wt, Wi, exp_W, ds_W1, rt_W1, out_W,
      exp_b, ds_b1, rt_b1,
      textb, imgb, Wtb, Wib, Bcat, outWb, biascat);

  dim3 blk(256);
  // 2. comb = [gelu(text@Wt.T+bt), gelu(image@Wi.T+bi)] -> bf16 [B,1024]
  gemm_proj<<<dim3(PDIM / 128, BDIM / 128, 2), blk, 0, stream>>>(
      textb, imgb, Wtb, Wib, bt, bi, comb);
  // 3. Hall = gelu(comb @ [exp_W;ds_W1;rt_W1].T + bias) -> bf16 [B,5376]
  //    256^2 8-phase tile (NCAT = 21*256, K = 32*32)
  gemm256<0><<<dim3(NCAT / 256, BDIM / 256), dim3(512), 0, stream>>>(
      comb, 1024, Bcat, 1024, Hall, NCAT, 1024, biascat, nullptr);
  // 4. router probs + ds + fused hidden (single pass over Hall)
  moe_mix<<<BDIM, 256, 0, stream>>>(Hall, rt_W2, rt_b2, ds_W2, ds_b2,
                                    out_probs, out_ds, fused);
  // 5. residual = fused @ out_W.T + out_b -> f32 [B,768]
  gemm_bt<1><<<dim3(FDIM / 128, BDIM / 128), blk, 0, stream>>>(
      fused, 1024, outWb, 1024, resid, FDIM, 1024, out_b, nullptr);
  // 6. pred + tgt normalize in one launch
  normalize_both<<<BDIM + TDIM, 256, 0, stream>>>(
      text, image, out_ds, resid, target, pred, tgtb);
  // 7. logits = exp(logit_scale) * pred @ tgt.T -> f32 [B,T]
  //    256^2 8-phase tile (8192 = 32*256, K = 24*32)
  gemm256<2><<<dim3(TDIM / 256, BDIM / 256), dim3(512), 0, stream>>>(
      pred, FDIM, tgtb, FDIM, out_logits, TDIM, FDIM, nullptr, logit_scale);
}

// Round 3
// 700.874 us; speedup vs baseline: 1.1499x; 1.1499x over previous
//
#include <hip/hip_runtime.h>
#include <stdint.h>
#include <math.h>

// Problem dims
#define BDIM 8192
#define TDIM 8192
#define FDIM 768
#define PDIM 512
#define HDIM 1024
#define NEXP 4
#define NCAT 5376  // 4*1024 (experts) + 1024 (ds) + 256 (router)

using short4v = __attribute__((ext_vector_type(4))) short;
using short8 = __attribute__((ext_vector_type(8))) short;
using f32x4  = __attribute__((ext_vector_type(4))) float;

__device__ __forceinline__ short f2bf(float f) {
  uint32_t u = __builtin_bit_cast(uint32_t, f);
  u += 0x7fffu + ((u >> 16) & 1u);   // RNE
  return (short)(u >> 16);
}
__device__ __forceinline__ float bf2f(short s) {
  uint32_t u = ((uint32_t)(uint16_t)s) << 16;
  return __builtin_bit_cast(float, u);
}
__device__ __forceinline__ float gelu_exact(float x) {
  return 0.5f * x * (1.0f + erff(x * 0.70710678118654752f));
}

#define GLDS(gp, lp) __builtin_amdgcn_global_load_lds( \
    (const __attribute__((address_space(1))) void*)(gp), \
    (__attribute__((address_space(3))) void*)(lp), 16, 0, 0)

// XCD-aware block remap (T1): dispatch slot s lands on XCD s%8 (round-robin);
// give each XCD a CONTIGUOUS chunk of tiles so consecutive tiles (sharing the
// A row-panel) hit the same private L2.  Requires gx*gy % 8 == 0.
__device__ __forceinline__ void xcd_remap(int gx, int gy, int& bx, int& by) {
  const int lin = blockIdx.y * gx + blockIdx.x;   // dispatch-order id
  const int cpx = (gx * gy) >> 3;
  const int tl  = (lin & 7) * cpx + (lin >> 3);   // tile to compute
  bx = tl % gx;
  by = tl / gx;
}

// ---------------------------------------------------------------------------
// Shared GEMM body: C[M,N] = A[M,K] @ B[N,K]^T (row-major bf16-as-short).
// 128x128 block tile, 4 waves, 4x4 of 16x16x32 MFMA each, BK=32. (m97-style,
// proven 667us baseline structure.)
// MODE 0: +bias[col], gelu, store bf16
// MODE 1: +bias[col], store f32
// MODE 2: *scale, store f32
// ---------------------------------------------------------------------------
template <int MODE>
__device__ __forceinline__ void gemm_body(
    const short* __restrict__ A, int lda,
    const short* __restrict__ B, int ldb,
    void* __restrict__ C, int ldc, int K,
    const float* __restrict__ bias, float scale,
    int m0, int n0)
{
  __shared__ short sA[4096];  // 128 x 32
  __shared__ short sB[4096];
  const int t    = threadIdx.x;
  const int lane = t & 63;
  const int wave = t >> 6;
  const int wm = (wave >> 1) * 64;
  const int wn = (wave & 1) * 64;
  const int l15  = lane & 15;
  const int quad = lane >> 4;

  f32x4 acc[4][4];
#pragma unroll
  for (int i = 0; i < 4; ++i)
#pragma unroll
    for (int j = 0; j < 4; ++j)
      acc[i][j] = (f32x4){0.f, 0.f, 0.f, 0.f};

  const int rr = t >> 2;
  const int cc = (t & 3) * 8;
  const short* gA0 = A + (size_t)(m0 + rr) * lda + cc;
  const short* gA1 = A + (size_t)(m0 + 64 + rr) * lda + cc;
  const short* gB0 = B + (size_t)(n0 + rr) * ldb + cc;
  const short* gB1 = B + (size_t)(n0 + 64 + rr) * ldb + cc;
  short* lA0 = sA + t * 8;
  short* lA1 = sA + 2048 + t * 8;
  short* lB0 = sB + t * 8;
  short* lB1 = sB + 2048 + t * 8;

  for (int k0 = 0; k0 < K; k0 += 32) {
    GLDS(gA0 + k0, lA0);
    GLDS(gA1 + k0, lA1);
    GLDS(gB0 + k0, lB0);
    GLDS(gB1 + k0, lB1);
    __syncthreads();
    short8 af[4], bfr[4];
#pragma unroll
    for (int i = 0; i < 4; ++i)
      af[i] = *(const short8*)(sA + (wm + i * 16 + l15) * 32 + quad * 8);
#pragma unroll
    for (int j = 0; j < 4; ++j)
      bfr[j] = *(const short8*)(sB + (wn + j * 16 + l15) * 32 + quad * 8);
#pragma unroll
    for (int i = 0; i < 4; ++i)
#pragma unroll
      for (int j = 0; j < 4; ++j)
        acc[i][j] = __builtin_amdgcn_mfma_f32_16x16x32_bf16(af[i], bfr[j], acc[i][j], 0, 0, 0);
    __syncthreads();
  }

#pragma unroll
  for (int i = 0; i < 4; ++i) {
#pragma unroll
    for (int j = 0; j < 4; ++j) {
      const int col = n0 + wn + j * 16 + l15;
      float bv = (MODE == 2) ? 0.f : bias[col];
#pragma unroll
      for (int r = 0; r < 4; ++r) {
        const int row = m0 + wm + i * 16 + quad * 4 + r;  // C/D: col=lane&15, row=quad*4+reg
        float v = acc[i][j][r];
        if (MODE == 0) {
          v = gelu_exact(v + bv);
          ((short*)C)[(size_t)row * ldc + col] = f2bf(v);
        } else if (MODE == 1) {
          ((float*)C)[(size_t)row * ldc + col] = v + bv;
        } else {
          ((float*)C)[(size_t)row * ldc + col] = v * scale;
        }
      }
    }
  }
}

template <int MODE>
__global__ __launch_bounds__(256, 2)
void gemm_bt(const short* __restrict__ A, int lda,
             const short* __restrict__ B, int ldb,
             void* __restrict__ C, int ldc, int K,
             const float* __restrict__ bias,
             const float* __restrict__ scale_ptr)
{
  float scale = 1.f;
  if (MODE == 2) scale = expf(scale_ptr[0]);
  int bx, by;
  xcd_remap(gridDim.x, gridDim.y, bx, by);
  gemm_body<MODE>(A, lda, B, ldb, C, ldc, K, bias, scale, by * 128, bx * 128);
}

// both projections in one launch: z=0 -> text@Wt.T (cols 0..511),
// z=1 -> image@Wi.T (cols 512..1023); C is comb [B,1024] bf16
__global__ __launch_bounds__(256, 2)
void gemm_proj(const short* __restrict__ textb, const short* __restrict__ imgb,
               const short* __restrict__ Wtb, const short* __restrict__ Wib,
               const float* __restrict__ bt, const float* __restrict__ bi,
               short* __restrict__ comb)
{
  const int z = blockIdx.z;
  const short* A = z ? imgb : textb;
  const short* B = z ? Wib : Wtb;
  const float* bias = z ? bi : bt;
  short* C = comb + (z ? 512 : 0);
  int bx, by;
  xcd_remap(gridDim.x, gridDim.y, bx, by);
  gemm_body<0>(A, FDIM, B, FDIM, C, 1024, FDIM, bias, 1.f, by * 128, bx * 128);
}

// ---------------------------------------------------------------------------
// One kernel for ALL f32->bf16 conversions + bias concat. Flat grid over
// vec4 units with hardcoded segment boundaries.
// ---------------------------------------------------------------------------
#define SEG0 1572864u   // text   (8192*768/4)
#define SEG1 3145728u   // image
#define SEG2 3244032u   // Wt     (512*768/4)
#define SEG3 3342336u   // Wi
#define SEG4 4390912u   // exp_W  (4*1024*1024/4)
#define SEG5 4653056u   // ds_W1  (1024*1024/4)
#define SEG6 4718592u   // rt_W1  (256*1024/4)
#define SEG7 4915200u   // out_W  (768*1024/4)
#define SEG8 4916544u   // bias concat (5376/4)

__global__ __launch_bounds__(256)
void prep_all(const float* __restrict__ text, const float* __restrict__ image,
              const float* __restrict__ Wt, const float* __restrict__ Wi,
              const float* __restrict__ exp_W, const float* __restrict__ ds_W1,
              const float* __restrict__ rt_W1, const float* __restrict__ out_W,
              const float* __restrict__ exp_b, const float* __restrict__ ds_b1,
              const float* __restrict__ rt_b1,
              short* __restrict__ textb, short* __restrict__ imgb,
              short* __restrict__ Wtb, short* __restrict__ Wib,
              short* __restrict__ Bcat, short* __restrict__ outWb,
              float* __restrict__ biascat)
{
  const uint32_t i = blockIdx.x * 256 + threadIdx.x;
  if (i >= SEG8) return;
  if (i >= SEG7) {  // bias concat (f32 -> f32)
    const uint32_t j = (i - SEG7) * 4;
#pragma unroll
    for (int k = 0; k < 4; ++k) {
      uint32_t idx = j + k;
      float v;
      if (idx < 4096)      v = exp_b[idx];
      else if (idx < 5120) v = ds_b1[idx - 4096];
      else                 v = rt_b1[idx - 5120];
      biascat[idx] = v;
    }
    return;
  }
  const float* s;
  short* d;
  uint32_t j;
  if (i < SEG1) {
    if (i < SEG0) { j = i;        s = text;  d = textb; }
    else          { j = i - SEG0; s = image; d = imgb;  }
  } else if (i < SEG3) {
    if (i < SEG2) { j = i - SEG1; s = Wt; d = Wtb; }
    else          { j = i - SEG2; s = Wi; d = Wib; }
  } else if (i < SEG5) {
    if (i < SEG4) { j = i - SEG3; s = exp_W; d = Bcat; }
    else          { j = i - SEG4; s = ds_W1; d = Bcat + (size_t)4096 * 1024; }
  } else {
    if (i < SEG6) { j = i - SEG5; s = rt_W1; d = Bcat + (size_t)5120 * 1024; }
    else          { j = i - SEG6; s = out_W; d = outWb; }
  }
  float4 v = ((const float4*)s)[j];
  short4v o = { f2bf(v.x), f2bf(v.y), f2bf(v.z), f2bf(v.w) };
  ((short4v*)d)[j] = o;
}

// ---------------------------------------------------------------------------
// Fused router + ds scalar + expert mixing. One block (256 thr) per row.
// All Hall reads vectorized to short4 (8B/lane) per Guideline 13.
// ---------------------------------------------------------------------------
__global__ __launch_bounds__(256)
void moe_mix(const short* __restrict__ Hall,
             const float* __restrict__ rt_W2, const float* __restrict__ rt_b2,
             const float* __restrict__ ds_W2, const float* __restrict__ ds_b2,
             float* __restrict__ out_probs, float* __restrict__ out_ds,
             short* __restrict__ fused)
{
  const int b = blockIdx.x;
  const int t = threadIdx.x;
  const int lane = t & 63;
  const int wave = t >> 6;
  const short* h = Hall + (size_t)b * NCAT;
  const int t4 = t * 4;

  // router partials (256 elems, one per thread)
  float rv = bf2f(h[5120 + t]);
  float p0 = rv * rt_W2[t];
  float p1 = rv * rt_W2[256 + t];
  float p2 = rv * rt_W2[512 + t];
  float p3 = rv * rt_W2[768 + t];
  // ds partials: 1024 elems, short4 per thread
  short4v hd = *(const short4v*)(h + 4096 + t4);
  float4 wd = *(const float4*)(ds_W2 + t4);
  float dd = bf2f(hd[0]) * wd.x + bf2f(hd[1]) * wd.y
           + bf2f(hd[2]) * wd.z + bf2f(hd[3]) * wd.w;

#pragma unroll
  for (int off = 32; off; off >>= 1) {
    p0 += __shfl_xor(p0, off);
    p1 += __shfl_xor(p1, off);
    p2 += __shfl_xor(p2, off);
    p3 += __shfl_xor(p3, off);
    dd += __shfl_xor(dd, off);
  }
  __shared__ float red[5][4];
  __shared__ float bc[5];
  if (lane == 0) {
    red[0][wave] = p0; red[1][wave] = p1; red[2][wave] = p2;
    red[3][wave] = p3; red[4][wave] = dd;
  }
  __syncthreads();
  if (t == 0) {
    float l0 = red[0][0] + red[0][1] + red[0][2] + red[0][3] + rt_b2[0];
    float l1 = red[1][0] + red[1][1] + red[1][2] + red[1][3] + rt_b2[1];
    float l2 = red[2][0] + red[2][1] + red[2][2] + red[2][3] + rt_b2[2];
    float l3 = red[3][0] + red[3][1] + red[3][2] + red[3][3] + rt_b2[3];
    float d  = red[4][0] + red[4][1] + red[4][2] + red[4][3] + ds_b2[0];
    float mx = fmaxf(fmaxf(l0, l1), fmaxf(l2, l3));
    float e0 = expf(l0 - mx), e1 = expf(l1 - mx);
    float e2 = expf(l2 - mx), e3 = expf(l3 - mx);
    float inv = 1.f / (e0 + e1 + e2 + e3);
    bc[0] = e0 * inv; bc[1] = e1 * inv; bc[2] = e2 * inv; bc[3] = e3 * inv;
    bc[4] = 1.f / (1.f + expf(-d));
    out_probs[b * 4 + 0] = bc[0];
    out_probs[b * 4 + 1] = bc[1];
    out_probs[b * 4 + 2] = bc[2];
    out_probs[b * 4 + 3] = bc[3];
    out_ds[b] = bc[4];
  }
  __syncthreads();
  const float q0 = bc[0], q1 = bc[1], q2 = bc[2], q3 = bc[3];
  // expert mix: 1024 cols, short4 per thread per expert
  short4v a0 = *(const short4v*)(h + t4);
  short4v a1 = *(const short4v*)(h + 1024 + t4);
  short4v a2 = *(const short4v*)(h + 2048 + t4);
  short4v a3 = *(const short4v*)(h + 3072 + t4);
  short4v o;
#pragma unroll
  for (int k = 0; k < 4; ++k) {
    float v = q0 * bf2f(a0[k]) + q1 * bf2f(a1[k])
            + q2 * bf2f(a2[k]) + q3 * bf2f(a3[k]);
    o[k] = f2bf(v);
  }
  *(short4v*)(fused + (size_t)b * 1024 + t4) = o;
}

// ---------------------------------------------------------------------------
// Both normalizes in one launch, float4 loads (192 thr x float4 = 768 f32).
// blocks [0,BDIM): pred (combine+normalize); [BDIM,BDIM+TDIM): tgt normalize.
// ---------------------------------------------------------------------------
__global__ __launch_bounds__(192)
void normalize_both(const float* __restrict__ text, const float* __restrict__ image,
                    const float* __restrict__ ds, const float* __restrict__ resid,
                    const float* __restrict__ target,
                    short* __restrict__ pred, short* __restrict__ tgtb)
{
  const int bb = blockIdx.x;
  const int t = threadIdx.x;   // 0..191
  float4 o;
  short* d;
  if (bb < BDIM) {
    const float dv = ds[bb];
    const float4 a = ((const float4*)(text  + (size_t)bb * FDIM))[t];
    const float4 m = ((const float4*)(image + (size_t)bb * FDIM))[t];
    const float4 s = ((const float4*)(resid + (size_t)bb * FDIM))[t];
    o.x = dv * a.x + (1.f - dv) * m.x + s.x;
    o.y = dv * a.y + (1.f - dv) * m.y + s.y;
    o.z = dv * a.z + (1.f - dv) * m.z + s.z;
    o.w = dv * a.w + (1.f - dv) * m.w + s.w;
    d = pred + (size_t)bb * FDIM;
  } else {
    const int b = bb - BDIM;
    o = ((const float4*)(target + (size_t)b * FDIM))[t];
    d = tgtb + (size_t)b * FDIM;
  }
  float ss = o.x * o.x + o.y * o.y + o.z * o.z + o.w * o.w;
  __shared__ float red[3];
#pragma unroll
  for (int off = 32; off; off >>= 1) ss += __shfl_xor(ss, off);
  if ((t & 63) == 0) red[t >> 6] = ss;
  __syncthreads();
  const float tot = red[0] + red[1] + red[2];
  const float rn = 1.f / fmaxf(sqrtf(tot), 1e-12f);
  short4v r = { f2bf(o.x * rn), f2bf(o.y * rn), f2bf(o.z * rn), f2bf(o.w * rn) };
  ((short4v*)d)[t] = r;
}

// ---------------------------------------------------------------------------
extern "C" void kernel_launch(void* const* d_in, const int* in_sizes, int n_in,
                              void* d_out, int out_size, void* d_ws, size_t ws_size,
                              hipStream_t stream) {
  const float* image  = (const float*)d_in[0];
  const float* text   = (const float*)d_in[1];
  const float* target = (const float*)d_in[2];
  const float* Wt     = (const float*)d_in[3];
  const float* bt     = (const float*)d_in[4];
  const float* Wi     = (const float*)d_in[5];
  const float* bi     = (const float*)d_in[6];
  const float* ds_W1  = (const float*)d_in[7];
  const float* ds_b1  = (const float*)d_in[8];
  const float* ds_W2  = (const float*)d_in[9];
  const float* ds_b2  = (const float*)d_in[10];
  const float* exp_W  = (const float*)d_in[11];
  const float* exp_b  = (const float*)d_in[12];
  const float* rt_W1  = (const float*)d_in[13];
  const float* rt_b1  = (const float*)d_in[14];
  const float* rt_W2  = (const float*)d_in[15];
  const float* rt_b2  = (const float*)d_in[16];
  const float* out_W  = (const float*)d_in[17];
  const float* out_b  = (const float*)d_in[18];
  const float* logit_scale = (const float*)d_in[19];

  char* ws = (char*)d_ws;
  short* comb  = (short*)ws;  ws += (size_t)BDIM * 1024 * 2;
  short* Hall  = (short*)ws;  ws += (size_t)BDIM * NCAT * 2;
  short* fused = (short*)ws;  ws += (size_t)BDIM * 1024 * 2;
  float* resid = (float*)ws;  ws += (size_t)BDIM * FDIM * 4;
  short* pred  = (short*)ws;  ws += (size_t)BDIM * FDIM * 2;
  short* tgtb  = (short*)ws;  ws += (size_t)TDIM * FDIM * 2;
  short* textb = (short*)ws;  ws += (size_t)BDIM * FDIM * 2;
  short* imgb  = (short*)ws;  ws += (size_t)BDIM * FDIM * 2;
  short* Wtb   = (short*)ws;  ws += (size_t)PDIM * FDIM * 2;
  short* Wib   = (short*)ws;  ws += (size_t)PDIM * FDIM * 2;
  short* outWb = (short*)ws;  ws += (size_t)FDIM * HDIM * 2;
  short* Bcat  = (short*)ws;  ws += (size_t)NCAT * HDIM * 2;
  float* biascat = (float*)ws; ws += (size_t)NCAT * 4;

  float* out_logits = (float*)d_out;
  float* out_ds     = out_logits + (size_t)BDIM * TDIM;
  float* out_probs  = out_ds + BDIM;

  // 1. all conversions + bias concat in one launch
  prep_all<<<(SEG8 + 255) / 256, 256, 0, stream>>>(
      text, image, Wt, Wi, exp_W, ds_W1, rt_W1, out_W,
      exp_b, ds_b1, rt_b1,
      textb, imgb, Wtb, Wib, Bcat, outWb, biascat);

  dim3 blk(256);
  // 2. comb = [gelu(text@Wt.T+bt), gelu(image@Wi.T+bi)] -> bf16 [B,1024]
  gemm_proj<<<dim3(PDIM / 128, BDIM / 128, 2), blk, 0, stream>>>(
      textb, imgb, Wtb, Wib, bt, bi, comb);
  // 3. Hall = gelu(comb @ [exp_W;ds_W1;rt_W1].T + bias) -> bf16 [B,5376]
  gemm_bt<0><<<dim3(NCAT / 128, BDIM / 128), blk, 0, stream>>>(
      comb, 1024, Bcat, 1024, Hall, NCAT, 1024, biascat, nullptr);
  // 4. router probs + ds + fused hidden (single pass over Hall)
  moe_mix<<<BDIM, 256, 0, stream>>>(Hall, rt_W2, rt_b2, ds_W2, ds_b2,
                                    out_probs, out_ds, fused);
  // 5. residual = fused @ out_W.T + out_b -> f32 [B,768]
  gemm_bt<1><<<dim3(FDIM / 128, BDIM / 128), blk, 0, stream>>>(
      fused, 1024, outWb, 1024, resid, FDIM, 1024, out_b, nullptr);
  // 6. pred + tgt normalize in one launch
  normalize_both<<<BDIM + TDIM, 192, 0, stream>>>(
      text, image, out_ds, resid, target, pred, tgtb);
  // 7. logits = exp(logit_scale) * pred @ tgt.T -> f32 [B,T]
  gemm_bt<2><<<dim3(TDIM / 128, BDIM / 128), blk, 0, stream>>>(
      pred, FDIM, tgtb, FDIM, out_logits, TDIM, FDIM, nullptr, logit_scale);
}

// Round 4
// 666.452 us; speedup vs baseline: 1.2093x; 1.0517x over previous
//
#include <hip/hip_runtime.h>
#include <stdint.h>
#include <math.h>

// Problem dims
#define BDIM 8192
#define TDIM 8192
#define FDIM 768
#define PDIM 512
#define HDIM 1024
#define NEXP 4
#define NCAT 5376  // 4*1024 (experts) + 1024 (ds) + 256 (router)

using short4v = __attribute__((ext_vector_type(4))) short;
using short8 = __attribute__((ext_vector_type(8))) short;
using f32x4  = __attribute__((ext_vector_type(4))) float;

__device__ __forceinline__ short f2bf(float f) {
  uint32_t u = __builtin_bit_cast(uint32_t, f);
  u += 0x7fffu + ((u >> 16) & 1u);   // RNE
  return (short)(u >> 16);
}
__device__ __forceinline__ float bf2f(short s) {
  uint32_t u = ((uint32_t)(uint16_t)s) << 16;
  return __builtin_bit_cast(float, u);
}
__device__ __forceinline__ float gelu_exact(float x) {
  return 0.5f * x * (1.0f + erff(x * 0.70710678118654752f));
}

#define GLDS(gp, lp) __builtin_amdgcn_global_load_lds( \
    (const __attribute__((address_space(1))) void*)(gp), \
    (__attribute__((address_space(3))) void*)(lp), 16, 0, 0)

// ---------------------------------------------------------------------------
// Shared GEMM body: C[M,N] = A[M,K] @ B[N,K]^T (row-major bf16-as-short).
// 128x128 block tile, 4 waves, 4x4 of 16x16x32 MFMA each, BK=32. (m97-style,
// proven 667us baseline structure.)  DEFAULT block order: with gridDim.x=N/128
// divisible by 8, each XCD sees a fixed subset of B-panel columns -> B-panel
// reuse is already L2-resident; do NOT remap (round-3 lesson: remap tripled
// FETCH_SIZE).
// MODE 0: +bias[col], gelu, store bf16
// MODE 1: +bias[col], store f32
// MODE 2: *scale, store f32
// ---------------------------------------------------------------------------
template <int MODE>
__device__ __forceinline__ void gemm_body(
    const short* __restrict__ A, int lda,
    const short* __restrict__ B, int ldb,
    void* __restrict__ C, int ldc, int K,
    const float* __restrict__ bias, float scale,
    int m0, int n0)
{
  __shared__ short sA[4096];  // 128 x 32
  __shared__ short sB[4096];
  const int t    = threadIdx.x;
  const int lane = t & 63;
  const int wave = t >> 6;
  const int wm = (wave >> 1) * 64;
  const int wn = (wave & 1) * 64;
  const int l15  = lane & 15;
  const int quad = lane >> 4;

  f32x4 acc[4][4];
#pragma unroll
  for (int i = 0; i < 4; ++i)
#pragma unroll
    for (int j = 0; j < 4; ++j)
      acc[i][j] = (f32x4){0.f, 0.f, 0.f, 0.f};

  const int rr = t >> 2;
  const int cc = (t & 3) * 8;
  const short* gA0 = A + (size_t)(m0 + rr) * lda + cc;
  const short* gA1 = A + (size_t)(m0 + 64 + rr) * lda + cc;
  const short* gB0 = B + (size_t)(n0 + rr) * ldb + cc;
  const short* gB1 = B + (size_t)(n0 + 64 + rr) * ldb + cc;
  short* lA0 = sA + t * 8;
  short* lA1 = sA + 2048 + t * 8;
  short* lB0 = sB + t * 8;
  short* lB1 = sB + 2048 + t * 8;

  for (int k0 = 0; k0 < K; k0 += 32) {
    GLDS(gA0 + k0, lA0);
    GLDS(gA1 + k0, lA1);
    GLDS(gB0 + k0, lB0);
    GLDS(gB1 + k0, lB1);
    __syncthreads();
    short8 af[4], bfr[4];
#pragma unroll
    for (int i = 0; i < 4; ++i)
      af[i] = *(const short8*)(sA + (wm + i * 16 + l15) * 32 + quad * 8);
#pragma unroll
    for (int j = 0; j < 4; ++j)
      bfr[j] = *(const short8*)(sB + (wn + j * 16 + l15) * 32 + quad * 8);
#pragma unroll
    for (int i = 0; i < 4; ++i)
#pragma unroll
      for (int j = 0; j < 4; ++j)
        acc[i][j] = __builtin_amdgcn_mfma_f32_16x16x32_bf16(af[i], bfr[j], acc[i][j], 0, 0, 0);
    __syncthreads();
  }

#pragma unroll
  for (int i = 0; i < 4; ++i) {
#pragma unroll
    for (int j = 0; j < 4; ++j) {
      const int col = n0 + wn + j * 16 + l15;
      float bv = (MODE == 2) ? 0.f : bias[col];
#pragma unroll
      for (int r = 0; r < 4; ++r) {
        const int row = m0 + wm + i * 16 + quad * 4 + r;  // C/D: col=lane&15, row=quad*4+reg
        float v = acc[i][j][r];
        if (MODE == 0) {
          v = gelu_exact(v + bv);
          ((short*)C)[(size_t)row * ldc + col] = f2bf(v);
        } else if (MODE == 1) {
          ((float*)C)[(size_t)row * ldc + col] = v + bv;
        } else {
          ((float*)C)[(size_t)row * ldc + col] = v * scale;
        }
      }
    }
  }
}

template <int MODE>
__global__ __launch_bounds__(256, 2)
void gemm_bt(const short* __restrict__ A, int lda,
             const short* __restrict__ B, int ldb,
             void* __restrict__ C, int ldc, int K,
             const float* __restrict__ bias,
             const float* __restrict__ scale_ptr)
{
  float scale = 1.f;
  if (MODE == 2) scale = expf(scale_ptr[0]);
  gemm_body<MODE>(A, lda, B, ldb, C, ldc, K, bias, scale,
                  blockIdx.y * 128, blockIdx.x * 128);
}

// both projections in one launch: z=0 -> text@Wt.T (cols 0..511),
// z=1 -> image@Wi.T (cols 512..1023); C is comb [B,1024] bf16
__global__ __launch_bounds__(256, 2)
void gemm_proj(const short* __restrict__ textb, const short* __restrict__ imgb,
               const short* __restrict__ Wtb, const short* __restrict__ Wib,
               const float* __restrict__ bt, const float* __restrict__ bi,
               short* __restrict__ comb)
{
  const int z = blockIdx.z;
  const short* A = z ? imgb : textb;
  const short* B = z ? Wib : Wtb;
  const float* bias = z ? bi : bt;
  short* C = comb + (z ? 512 : 0);
  gemm_body<0>(A, FDIM, B, FDIM, C, 1024, FDIM, bias, 1.f,
               blockIdx.y * 128, blockIdx.x * 128);
}

// ---------------------------------------------------------------------------
// One kernel for ALL f32->bf16 conversions + bias concat. Flat grid over
// vec4 units with hardcoded segment boundaries.
// ---------------------------------------------------------------------------
#define SEG0 1572864u   // text   (8192*768/4)
#define SEG1 3145728u   // image
#define SEG2 3244032u   // Wt     (512*768/4)
#define SEG3 3342336u   // Wi
#define SEG4 4390912u   // exp_W  (4*1024*1024/4)
#define SEG5 4653056u   // ds_W1  (1024*1024/4)
#define SEG6 4718592u   // rt_W1  (256*1024/4)
#define SEG7 4915200u   // out_W  (768*1024/4)
#define SEG8 4916544u   // bias concat (5376/4)

__global__ __launch_bounds__(256)
void prep_all(const float* __restrict__ text, const float* __restrict__ image,
              const float* __restrict__ Wt, const float* __restrict__ Wi,
              const float* __restrict__ exp_W, const float* __restrict__ ds_W1,
              const float* __restrict__ rt_W1, const float* __restrict__ out_W,
              const float* __restrict__ exp_b, const float* __restrict__ ds_b1,
              const float* __restrict__ rt_b1,
              short* __restrict__ textb, short* __restrict__ imgb,
              short* __restrict__ Wtb, short* __restrict__ Wib,
              short* __restrict__ Bcat, short* __restrict__ outWb,
              float* __restrict__ biascat)
{
  const uint32_t i = blockIdx.x * 256 + threadIdx.x;
  if (i >= SEG8) return;
  if (i >= SEG7) {  // bias concat (f32 -> f32)
    const uint32_t j = (i - SEG7) * 4;
#pragma unroll
    for (int k = 0; k < 4; ++k) {
      uint32_t idx = j + k;
      float v;
      if (idx < 4096)      v = exp_b[idx];
      else if (idx < 5120) v = ds_b1[idx - 4096];
      else                 v = rt_b1[idx - 5120];
      biascat[idx] = v;
    }
    return;
  }
  const float* s;
  short* d;
  uint32_t j;
  if (i < SEG1) {
    if (i < SEG0) { j = i;        s = text;  d = textb; }
    else          { j = i - SEG0; s = image; d = imgb;  }
  } else if (i < SEG3) {
    if (i < SEG2) { j = i - SEG1; s = Wt; d = Wtb; }
    else          { j = i - SEG2; s = Wi; d = Wib; }
  } else if (i < SEG5) {
    if (i < SEG4) { j = i - SEG3; s = exp_W; d = Bcat; }
    else          { j = i - SEG4; s = ds_W1; d = Bcat + (size_t)4096 * 1024; }
  } else {
    if (i < SEG6) { j = i - SEG5; s = rt_W1; d = Bcat + (size_t)5120 * 1024; }
    else          { j = i - SEG6; s = out_W; d = outWb; }
  }
  float4 v = ((const float4*)s)[j];
  short4v o = { f2bf(v.x), f2bf(v.y), f2bf(v.z), f2bf(v.w) };
  ((short4v*)d)[j] = o;
}

// ---------------------------------------------------------------------------
// Fused router + ds scalar + expert mixing. One block (256 thr) per row.
// All Hall reads vectorized to short4 (8B/lane) per Guideline 13.
// ---------------------------------------------------------------------------
__global__ __launch_bounds__(256)
void moe_mix(const short* __restrict__ Hall,
             const float* __restrict__ rt_W2, const float* __restrict__ rt_b2,
             const float* __restrict__ ds_W2, const float* __restrict__ ds_b2,
             float* __restrict__ out_probs, float* __restrict__ out_ds,
             short* __restrict__ fused)
{
  const int b = blockIdx.x;
  const int t = threadIdx.x;
  const int lane = t & 63;
  const int wave = t >> 6;
  const short* h = Hall + (size_t)b * NCAT;
  const int t4 = t * 4;

  // router partials (256 elems, one per thread)
  float rv = bf2f(h[5120 + t]);
  float p0 = rv * rt_W2[t];
  float p1 = rv * rt_W2[256 + t];
  float p2 = rv * rt_W2[512 + t];
  float p3 = rv * rt_W2[768 + t];
  // ds partials: 1024 elems, short4 per thread
  short4v hd = *(const short4v*)(h + 4096 + t4);
  float4 wd = *(const float4*)(ds_W2 + t4);
  float dd = bf2f(hd[0]) * wd.x + bf2f(hd[1]) * wd.y
           + bf2f(hd[2]) * wd.z + bf2f(hd[3]) * wd.w;

#pragma unroll
  for (int off = 32; off; off >>= 1) {
    p0 += __shfl_xor(p0, off);
    p1 += __shfl_xor(p1, off);
    p2 += __shfl_xor(p2, off);
    p3 += __shfl_xor(p3, off);
    dd += __shfl_xor(dd, off);
  }
  __shared__ float red[5][4];
  __shared__ float bc[5];
  if (lane == 0) {
    red[0][wave] = p0; red[1][wave] = p1; red[2][wave] = p2;
    red[3][wave] = p3; red[4][wave] = dd;
  }
  __syncthreads();
  if (t == 0) {
    float l0 = red[0][0] + red[0][1] + red[0][2] + red[0][3] + rt_b2[0];
    float l1 = red[1][0] + red[1][1] + red[1][2] + red[1][3] + rt_b2[1];
    float l2 = red[2][0] + red[2][1] + red[2][2] + red[2][3] + rt_b2[2];
    float l3 = red[3][0] + red[3][1] + red[3][2] + red[3][3] + rt_b2[3];
    float d  = red[4][0] + red[4][1] + red[4][2] + red[4][3] + ds_b2[0];
    float mx = fmaxf(fmaxf(l0, l1), fmaxf(l2, l3));
    float e0 = expf(l0 - mx), e1 = expf(l1 - mx);
    float e2 = expf(l2 - mx), e3 = expf(l3 - mx);
    float inv = 1.f / (e0 + e1 + e2 + e3);
    bc[0] = e0 * inv; bc[1] = e1 * inv; bc[2] = e2 * inv; bc[3] = e3 * inv;
    bc[4] = 1.f / (1.f + expf(-d));
    out_probs[b * 4 + 0] = bc[0];
    out_probs[b * 4 + 1] = bc[1];
    out_probs[b * 4 + 2] = bc[2];
    out_probs[b * 4 + 3] = bc[3];
    out_ds[b] = bc[4];
  }
  __syncthreads();
  const float q0 = bc[0], q1 = bc[1], q2 = bc[2], q3 = bc[3];
  // expert mix: 1024 cols, short4 per thread per expert
  short4v a0 = *(const short4v*)(h + t4);
  short4v a1 = *(const short4v*)(h + 1024 + t4);
  short4v a2 = *(const short4v*)(h + 2048 + t4);
  short4v a3 = *(const short4v*)(h + 3072 + t4);
  short4v o;
#pragma unroll
  for (int k = 0; k < 4; ++k) {
    float v = q0 * bf2f(a0[k]) + q1 * bf2f(a1[k])
            + q2 * bf2f(a2[k]) + q3 * bf2f(a3[k]);
    o[k] = f2bf(v);
  }
  *(short4v*)(fused + (size_t)b * 1024 + t4) = o;
}

// ---------------------------------------------------------------------------
// Both normalizes in one launch, float4 loads (192 thr x float4 = 768 f32).
// blocks [0,BDIM): pred (combine+normalize); [BDIM,BDIM+TDIM): tgt normalize.
// ---------------------------------------------------------------------------
__global__ __launch_bounds__(192)
void normalize_both(const float* __restrict__ text, const float* __restrict__ image,
                    const float* __restrict__ ds, const float* __restrict__ resid,
                    const float* __restrict__ target,
                    short* __restrict__ pred, short* __restrict__ tgtb)
{
  const int bb = blockIdx.x;
  const int t = threadIdx.x;   // 0..191
  float4 o;
  short* d;
  if (bb < BDIM) {
    const float dv = ds[bb];
    const float4 a = ((const float4*)(text  + (size_t)bb * FDIM))[t];
    const float4 m = ((const float4*)(image + (size_t)bb * FDIM))[t];
    const float4 s = ((const float4*)(resid + (size_t)bb * FDIM))[t];
    o.x = dv * a.x + (1.f - dv) * m.x + s.x;
    o.y = dv * a.y + (1.f - dv) * m.y + s.y;
    o.z = dv * a.z + (1.f - dv) * m.z + s.z;
    o.w = dv * a.w + (1.f - dv) * m.w + s.w;
    d = pred + (size_t)bb * FDIM;
  } else {
    const int b = bb - BDIM;
    o = ((const float4*)(target + (size_t)b * FDIM))[t];
    d = tgtb + (size_t)b * FDIM;
  }
  float ss = o.x * o.x + o.y * o.y + o.z * o.z + o.w * o.w;
  __shared__ float red[3];
#pragma unroll
  for (int off = 32; off; off >>= 1) ss += __shfl_xor(ss, off);
  if ((t & 63) == 0) red[t >> 6] = ss;
  __syncthreads();
  const float tot = red[0] + red[1] + red[2];
  const float rn = 1.f / fmaxf(sqrtf(tot), 1e-12f);
  short4v r = { f2bf(o.x * rn), f2bf(o.y * rn), f2bf(o.z * rn), f2bf(o.w * rn) };
  ((short4v*)d)[t] = r;
}

// ---------------------------------------------------------------------------
extern "C" void kernel_launch(void* const* d_in, const int* in_sizes, int n_in,
                              void* d_out, int out_size, void* d_ws, size_t ws_size,
                              hipStream_t stream) {
  const float* image  = (const float*)d_in[0];
  const float* text   = (const float*)d_in[1];
  const float* target = (const float*)d_in[2];
  const float* Wt     = (const float*)d_in[3];
  const float* bt     = (const float*)d_in[4];
  const float* Wi     = (const float*)d_in[5];
  const float* bi     = (const float*)d_in[6];
  const float* ds_W1  = (const float*)d_in[7];
  const float* ds_b1  = (const float*)d_in[8];
  const float* ds_W2  = (const float*)d_in[9];
  const float* ds_b2  = (const float*)d_in[10];
  const float* exp_W  = (const float*)d_in[11];
  const float* exp_b  = (const float*)d_in[12];
  const float* rt_W1  = (const float*)d_in[13];
  const float* rt_b1  = (const float*)d_in[14];
  const float* rt_W2  = (const float*)d_in[15];
  const float* rt_b2  = (const float*)d_in[16];
  const float* out_W  = (const float*)d_in[17];
  const float* out_b  = (const float*)d_in[18];
  const float* logit_scale = (const float*)d_in[19];

  char* ws = (char*)d_ws;
  short* comb  = (short*)ws;  ws += (size_t)BDIM * 1024 * 2;
  short* Hall  = (short*)ws;  ws += (size_t)BDIM * NCAT * 2;
  short* fused = (short*)ws;  ws += (size_t)BDIM * 1024 * 2;
  float* resid = (float*)ws;  ws += (size_t)BDIM * FDIM * 4;
  short* pred  = (short*)ws;  ws += (size_t)BDIM * FDIM * 2;
  short* tgtb  = (short*)ws;  ws += (size_t)TDIM * FDIM * 2;
  short* textb = (short*)ws;  ws += (size_t)BDIM * FDIM * 2;
  short* imgb  = (short*)ws;  ws += (size_t)BDIM * FDIM * 2;
  short* Wtb   = (short*)ws;  ws += (size_t)PDIM * FDIM * 2;
  short* Wib   = (short*)ws;  ws += (size_t)PDIM * FDIM * 2;
  short* outWb = (short*)ws;  ws += (size_t)FDIM * HDIM * 2;
  short* Bcat  = (short*)ws;  ws += (size_t)NCAT * HDIM * 2;
  float* biascat = (float*)ws; ws += (size_t)NCAT * 4;

  float* out_logits = (float*)d_out;
  float* out_ds     = out_logits + (size_t)BDIM * TDIM;
  float* out_probs  = out_ds + BDIM;

  // 1. all conversions + bias concat in one launch
  prep_all<<<(SEG8 + 255) / 256, 256, 0, stream>>>(
      text, image, Wt, Wi, exp_W, ds_W1, rt_W1, out_W,
      exp_b, ds_b1, rt_b1,
      textb, imgb, Wtb, Wib, Bcat, outWb, biascat);

  dim3 blk(256);
  // 2. comb = [gelu(text@Wt.T+bt), gelu(image@Wi.T+bi)] -> bf16 [B,1024]
  gemm_proj<<<dim3(PDIM / 128, BDIM / 128, 2), blk, 0, stream>>>(
      textb, imgb, Wtb, Wib, bt, bi, comb);
  // 3. Hall = gelu(comb @ [exp_W;ds_W1;rt_W1].T + bias) -> bf16 [B,5376]
  gemm_bt<0><<<dim3(NCAT / 128, BDIM / 128), blk, 0, stream>>>(
      comb, 1024, Bcat, 1024, Hall, NCAT, 1024, biascat, nullptr);
  // 4. router probs + ds + fused hidden (single pass over Hall)
  moe_mix<<<BDIM, 256, 0, stream>>>(Hall, rt_W2, rt_b2, ds_W2, ds_b2,
                                    out_probs, out_ds, fused);
  // 5. residual = fused @ out_W.T + out_b -> f32 [B,768]
  gemm_bt<1><<<dim3(FDIM / 128, BDIM / 128), blk, 0, stream>>>(
      fused, 1024, outWb, 1024, resid, FDIM, 1024, out_b, nullptr);
  // 6. pred + tgt normalize in one launch
  normalize_both<<<BDIM + TDIM, 192, 0, stream>>>(
      text, image, out_ds, resid, target, pred, tgtb);
  // 7. logits = exp(logit_scale) * pred @ tgt.T -> f32 [B,T]
  gemm_bt<2><<<dim3(TDIM / 128, BDIM / 128), blk, 0, stream>>>(
      pred, FDIM, tgtb, FDIM, out_logits, TDIM, FDIM, nullptr, logit_scale);
}